// Round 1
// baseline (508.842 us; speedup 1.0000x reference)
//
#include <hip/hip_runtime.h>
#include <math.h>

#define N_NODES 100000
#define N_EDGES 1600000
#define NFEAT 128
#define NHID 128
#define NS 64
#define NCLASS 16
#define BB 8192

#define SCAN_NB 391   // ceil(N_NODES / 256)

// ---------------- CSR build ----------------

__global__ __launch_bounds__(256) void hist_kernel(const int* __restrict__ row,
                                                   int* __restrict__ counts) {
  int i = blockIdx.x * blockDim.x + threadIdx.x;
  int stride = gridDim.x * blockDim.x;
  for (; i < N_EDGES; i += stride) atomicAdd(&counts[row[i]], 1);
}

__global__ __launch_bounds__(256) void partial_kernel(const int* __restrict__ counts,
                                                      int* __restrict__ bsum) {
  __shared__ int sd[256];
  int i = blockIdx.x * 256 + threadIdx.x;
  sd[threadIdx.x] = (i < N_NODES) ? counts[i] : 0;
  __syncthreads();
  for (int o = 128; o > 0; o >>= 1) {
    if (threadIdx.x < o) sd[threadIdx.x] += sd[threadIdx.x + o];
    __syncthreads();
  }
  if (threadIdx.x == 0) bsum[blockIdx.x] = sd[0];
}

__global__ __launch_bounds__(512) void scanp_kernel(const int* __restrict__ bsum,
                                                    int* __restrict__ bpre,
                                                    int* __restrict__ offs) {
  __shared__ int sd[512];
  int tid = threadIdx.x;
  int v = (tid < SCAN_NB) ? bsum[tid] : 0;
  sd[tid] = v;
  __syncthreads();
  for (int o = 1; o < 512; o <<= 1) {
    int add = (tid >= o) ? sd[tid - o] : 0;
    __syncthreads();
    sd[tid] += add;
    __syncthreads();
  }
  if (tid < SCAN_NB) bpre[tid] = sd[tid] - v;        // exclusive prefix of block sums
  if (tid == SCAN_NB - 1) offs[N_NODES] = sd[tid];   // total edge count
}

__global__ __launch_bounds__(256) void apply_kernel(const int* __restrict__ counts,
                                                    const int* __restrict__ bpre,
                                                    int* __restrict__ offs,
                                                    int* __restrict__ cursor) {
  __shared__ int sd[256];
  int tid = threadIdx.x;
  int i = blockIdx.x * 256 + tid;
  int v = (i < N_NODES) ? counts[i] : 0;
  sd[tid] = v;
  __syncthreads();
  for (int o = 1; o < 256; o <<= 1) {
    int add = (tid >= o) ? sd[tid - o] : 0;
    __syncthreads();
    sd[tid] += add;
    __syncthreads();
  }
  int off = bpre[blockIdx.x] + sd[tid] - v;  // global exclusive prefix
  if (i < N_NODES) {
    offs[i] = off;
    cursor[i] = off;
  }
}

__global__ __launch_bounds__(256) void scatter_kernel(const int* __restrict__ row,
                                                      const int* __restrict__ col,
                                                      const float* __restrict__ val,
                                                      int* __restrict__ cursor,
                                                      int* __restrict__ ecol,
                                                      float* __restrict__ evalv) {
  int i = blockIdx.x * blockDim.x + threadIdx.x;
  int stride = gridDim.x * blockDim.x;
  for (; i < N_EDGES; i += stride) {
    int r = row[i];
    int p = atomicAdd(&cursor[r], 1);
    ecol[p] = col[i];
    evalv[p] = val[i];
  }
}

// ---------------- dense GEMM: C[nr,128] = A[nr,128] @ W[128,128] (+bias) ----------------
// block = 256 threads, 32 rows per block; W staged in LDS in two 64-row halves (32 KB LDS
// -> 5 blocks/CU). Each thread computes a 4-row x 4-col register tile.

__device__ __forceinline__ void fma4(float4& acc, const float4& a,
                                     const float4& w0, const float4& w1,
                                     const float4& w2, const float4& w3) {
  acc.x = fmaf(a.x, w0.x, fmaf(a.y, w1.x, fmaf(a.z, w2.x, fmaf(a.w, w3.x, acc.x))));
  acc.y = fmaf(a.x, w0.y, fmaf(a.y, w1.y, fmaf(a.z, w2.y, fmaf(a.w, w3.y, acc.y))));
  acc.z = fmaf(a.x, w0.z, fmaf(a.y, w1.z, fmaf(a.z, w2.z, fmaf(a.w, w3.z, acc.z))));
  acc.w = fmaf(a.x, w0.w, fmaf(a.y, w1.w, fmaf(a.z, w2.w, fmaf(a.w, w3.w, acc.w))));
}

__global__ __launch_bounds__(256) void gemm128_kernel(const float* __restrict__ A,
                                                      const float* __restrict__ W,
                                                      const float* __restrict__ bias,
                                                      float* __restrict__ C,
                                                      int do_bias) {
  __shared__ float Ws[64 * 128];
  int tid = threadIdx.x;
  int c0 = (tid & 31) * 4;   // col 0..124 step 4
  int rg = tid >> 5;         // row group 0..7
  long rbase = (long)blockIdx.x * 32 + rg * 4;
  const float* A0 = A + rbase * 128;
  float4* Ws4 = (float4*)Ws;

  float4 acc0 = {0, 0, 0, 0}, acc1 = {0, 0, 0, 0}, acc2 = {0, 0, 0, 0}, acc3 = {0, 0, 0, 0};

  for (int half = 0; half < 2; ++half) {
    const float4* Wsrc = (const float4*)(W + half * 64 * 128);
#pragma unroll
    for (int i = 0; i < 8; ++i) Ws4[tid + i * 256] = Wsrc[tid + i * 256];
    __syncthreads();
    const float* Ah = A0 + half * 64;
#pragma unroll 4
    for (int k = 0; k < 64; k += 4) {
      float4 w0 = *(const float4*)&Ws[(k + 0) * 128 + c0];
      float4 w1 = *(const float4*)&Ws[(k + 1) * 128 + c0];
      float4 w2 = *(const float4*)&Ws[(k + 2) * 128 + c0];
      float4 w3 = *(const float4*)&Ws[(k + 3) * 128 + c0];
      float4 a0 = *(const float4*)(Ah + 0 * 128 + k);
      float4 a1 = *(const float4*)(Ah + 1 * 128 + k);
      float4 a2 = *(const float4*)(Ah + 2 * 128 + k);
      float4 a3 = *(const float4*)(Ah + 3 * 128 + k);
      fma4(acc0, a0, w0, w1, w2, w3);
      fma4(acc1, a1, w0, w1, w2, w3);
      fma4(acc2, a2, w0, w1, w2, w3);
      fma4(acc3, a3, w0, w1, w2, w3);
    }
    __syncthreads();
  }

  float4 bv = {0, 0, 0, 0};
  if (do_bias) bv = *(const float4*)&bias[c0];
  acc0.x += bv.x; acc0.y += bv.y; acc0.z += bv.z; acc0.w += bv.w;
  acc1.x += bv.x; acc1.y += bv.y; acc1.z += bv.z; acc1.w += bv.w;
  acc2.x += bv.x; acc2.y += bv.y; acc2.z += bv.z; acc2.w += bv.w;
  acc3.x += bv.x; acc3.y += bv.y; acc3.z += bv.z; acc3.w += bv.w;
  float* Cp = C + rbase * 128 + c0;
  *(float4*)(Cp + 0 * 128) = acc0;
  *(float4*)(Cp + 1 * 128) = acc1;
  *(float4*)(Cp + 2 * 128) = acc2;
  *(float4*)(Cp + 3 * 128) = acc3;
}

// ---------------- CSR spmm (one wave per row, 2 feats/lane) ----------------

__global__ __launch_bounds__(64) void spmm_row_kernel(const int* __restrict__ offs,
                                                      const int* __restrict__ ecol,
                                                      const float* __restrict__ evalv,
                                                      const float* __restrict__ a,
                                                      const float* __restrict__ bias,
                                                      float* __restrict__ h) {
  int r = blockIdx.x;
  int tid = threadIdx.x;
  int s = offs[r], e = offs[r + 1];
  float2 acc = {0.f, 0.f};
  for (int j = s; j < e; ++j) {
    int c = ecol[j];      // wave-uniform -> scalar load
    float v = evalv[j];   // wave-uniform -> scalar load
    float2 av = *(const float2*)(a + (long)c * 128 + tid * 2);
    acc.x = fmaf(v, av.x, acc.x);
    acc.y = fmaf(v, av.y, acc.y);
  }
  float2 bv = *(const float2*)(bias + tid * 2);
  float2 o;
  o.x = fmaxf(acc.x + bv.x, 0.f);
  o.y = fmaxf(acc.y + bv.y, 0.f);
  *(float2*)(h + (long)r * 128 + tid * 2) = o;
}

// spmm restricted to the 8192 selected rows (layer 2 aggregation, pre-GEMM)
__global__ __launch_bounds__(64) void spmm_sel_kernel(const int* __restrict__ offs,
                                                      const int* __restrict__ ecol,
                                                      const float* __restrict__ evalv,
                                                      const float* __restrict__ h1,
                                                      const int* __restrict__ index,
                                                      float* __restrict__ g2) {
  int b = blockIdx.x;
  int tid = threadIdx.x;
  int r = index[b];
  int s = offs[r], e = offs[r + 1];
  float2 acc = {0.f, 0.f};
  for (int j = s; j < e; ++j) {
    int c = ecol[j];
    float v = evalv[j];
    float2 av = *(const float2*)(h1 + (long)c * 128 + tid * 2);
    acc.x = fmaf(v, av.x, acc.x);
    acc.y = fmaf(v, av.y, acc.y);
  }
  *(float2*)(g2 + (long)b * 128 + tid * 2) = acc;
}

// ---------------- final: z = concat(t, s) @ Wl + bl; log_softmax ----------------

__global__ __launch_bounds__(128) void final_kernel(const float* __restrict__ t,
                                                    const float* __restrict__ s,
                                                    const float* __restrict__ Wl,
                                                    const float* __restrict__ bl,
                                                    float* __restrict__ out) {
  int b = blockIdx.x * 128 + threadIdx.x;  // 8192 threads exactly
  float z[16];
#pragma unroll
  for (int c = 0; c < 16; ++c) z[c] = bl[c];
  const float4* tb = (const float4*)(t + (long)b * 128);
#pragma unroll 4
  for (int k4 = 0; k4 < 32; ++k4) {
    float4 tv = tb[k4];
    const float* w = Wl + (k4 * 4) * 16;
#pragma unroll
    for (int c = 0; c < 16; ++c)
      z[c] += tv.x * w[c] + tv.y * w[16 + c] + tv.z * w[32 + c] + tv.w * w[48 + c];
  }
  const float4* sb = (const float4*)(s + (long)b * 64);
#pragma unroll 4
  for (int k4 = 0; k4 < 16; ++k4) {
    float4 sv = sb[k4];
    const float* w = Wl + (128 + k4 * 4) * 16;
#pragma unroll
    for (int c = 0; c < 16; ++c)
      z[c] += sv.x * w[c] + sv.y * w[16 + c] + sv.z * w[32 + c] + sv.w * w[48 + c];
  }
  float m = z[0];
#pragma unroll
  for (int c = 1; c < 16; ++c) m = fmaxf(m, z[c]);
  float sum = 0.f;
#pragma unroll
  for (int c = 0; c < 16; ++c) sum += expf(z[c] - m);
  float lse = m + logf(sum);
  float* ob = out + (long)b * 16;
#pragma unroll
  for (int c = 0; c < 16; ++c) ob[c] = z[c] - lse;
}

// ---------------- launch ----------------

extern "C" void kernel_launch(void* const* d_in, const int* in_sizes, int n_in,
                              void* d_out, int out_size, void* d_ws, size_t ws_size,
                              hipStream_t stream) {
  const float* s_in  = (const float*)d_in[0];
  const float* x     = (const float*)d_in[1];
  const int*   row   = (const int*)d_in[2];
  const int*   col   = (const int*)d_in[3];
  const float* val   = (const float*)d_in[4];
  const int*   index = (const int*)d_in[5];
  const float* W1    = (const float*)d_in[6];
  const float* b1    = (const float*)d_in[7];
  const float* W2    = (const float*)d_in[8];
  const float* b2    = (const float*)d_in[9];
  const float* Wl    = (const float*)d_in[10];
  const float* bl    = (const float*)d_in[11];
  float* out = (float*)d_out;

  // workspace carve (~124 MB)
  float* ws    = (float*)d_ws;
  float* a     = ws;                                // xW1          [100000,128]
  float* h1    = a    + (size_t)N_NODES * 128;      // layer1 out   [100000,128]
  float* g2    = h1   + (size_t)N_NODES * 128;      // sel spmm     [8192,128]
  float* tmat  = g2   + (size_t)BB * 128;           // g2@W2+b2     [8192,128]
  float* evalv = tmat + (size_t)BB * 128;           // CSR vals     [1.6M]
  int* counts  = (int*)(evalv + N_EDGES);           // [100000]
  int* offs    = counts + N_NODES;                  // [100001]
  int* cursor  = offs + (N_NODES + 1);              // [100000]
  int* ecol    = cursor + N_NODES;                  // [1.6M]
  int* bsum    = ecol + N_EDGES;                    // [391]
  int* bpre    = bsum + SCAN_NB;                    // [391]

  hipMemsetAsync(counts, 0, N_NODES * sizeof(int), stream);
  hist_kernel<<<1024, 256, 0, stream>>>(row, counts);
  partial_kernel<<<SCAN_NB, 256, 0, stream>>>(counts, bsum);
  scanp_kernel<<<1, 512, 0, stream>>>(bsum, bpre, offs);
  apply_kernel<<<SCAN_NB, 256, 0, stream>>>(counts, bpre, offs, cursor);
  scatter_kernel<<<1024, 256, 0, stream>>>(row, col, val, cursor, ecol, evalv);

  gemm128_kernel<<<N_NODES / 32, 256, 0, stream>>>(x, W1, nullptr, a, 0);
  spmm_row_kernel<<<N_NODES, 64, 0, stream>>>(offs, ecol, evalv, a, b1, h1);
  spmm_sel_kernel<<<BB, 64, 0, stream>>>(offs, ecol, evalv, h1, index, g2);
  gemm128_kernel<<<BB / 32, 256, 0, stream>>>(g2, W2, b2, tmat, 1);
  final_kernel<<<BB / 128, 128, 0, stream>>>(tmat, s_in, Wl, bl, out);
}